// Round 5
// baseline (209.832 us; speedup 1.0000x reference)
//
#include <hip/hip_runtime.h>
#include <math.h>

// VQ-VAE quantize: z [8,4096,512] f32, embed_w [1024,512] f32
// out = concat(z_q, diff, ind-as-f32)
//
// bf16 split-precision MFMA:  dot ~= zhi*ehi + zhi*elo + zlo*ehi
// score = ||e||^2 - 2*dot  (row-constant ||z||^2 dropped; argmin invariant)
// gemm: 128x128 tile, 4 waves, global_load_lds staging, 2-phase double-buffer
// (stage t+1 issued before compute of t; one barrier per k-tile).
// Scratch: ehi/elo/e2 in zq region (read before out-kernel writes it);
// zhi/zlo in diff region; pv/pif in d_ws (read by fused out-kernel).

#define D_DIM   512
#define K_CODES 1024
#define N_TOK   32768

#define BM 128
#define BN 128
#define NKT 16            // 512 / 32 bf16-cols per k-tile

typedef __attribute__((ext_vector_type(8))) short bf16x8;
typedef __attribute__((ext_vector_type(4))) float f32x4;

__device__ __forceinline__ unsigned short bf16_rne(float f) {
    unsigned int u = __float_as_uint(f);
    return (unsigned short)((u + 0x7FFFu + ((u >> 16) & 1u)) >> 16);
}
__device__ __forceinline__ float bf16_to_f32(unsigned short b) {
    return __uint_as_float(((unsigned int)b) << 16);
}

#define GLOAD16(gp, lp)                                                        \
    __builtin_amdgcn_global_load_lds(                                          \
        (const __attribute__((address_space(1))) void*)(gp),                   \
        (__attribute__((address_space(3))) void*)(lp), 16, 0, 0)

// ---------------- z -> zhi/zlo bf16 planes --------------------------------
__global__ __launch_bounds__(256) void vq_zsplit(const float* __restrict__ z,
                                                 unsigned short* __restrict__ zhi,
                                                 unsigned short* __restrict__ zlo) {
    const int tid = blockIdx.x * 256 + threadIdx.x;   // grid 2048
    const float4* z4 = (const float4*)z;
    ushort4* h4 = (ushort4*)zhi;
    ushort4* l4 = (ushort4*)zlo;
#pragma unroll
    for (int g = 0; g < 8; ++g) {
        const size_t i = (size_t)g * 524288 + tid;
        float4 v = z4[i];
        float f[4] = {v.x, v.y, v.z, v.w};
        unsigned short hb[4], lb[4];
#pragma unroll
        for (int j = 0; j < 4; ++j) {
            hb[j] = bf16_rne(f[j]);
            lb[j] = bf16_rne(f[j] - bf16_to_f32(hb[j]));
        }
        h4[i] = make_ushort4(hb[0], hb[1], hb[2], hb[3]);
        l4[i] = make_ushort4(lb[0], lb[1], lb[2], lb[3]);
    }
}

// ---------------- ew -> ehi/elo bf16 + e2 ---------------------------------
__global__ __launch_bounds__(256) void vq_prep(const float* __restrict__ ew,
                                               unsigned short* __restrict__ ehi,
                                               unsigned short* __restrict__ elo,
                                               float* __restrict__ e2) {
    const int wv = threadIdx.x >> 6, lane = threadIdx.x & 63;
    const int code = blockIdx.x * 4 + wv;          // grid 256
    const float* row = ew + (size_t)code * D_DIM;
    float s = 0.0f;
#pragma unroll
    for (int h = 0; h < 2; ++h) {
        const int c = h * 256 + lane * 4;
        float4 v = *(const float4*)(row + c);
        float f[4] = {v.x, v.y, v.z, v.w};
        unsigned short hb[4], lb[4];
#pragma unroll
        for (int j = 0; j < 4; ++j) {
            s = fmaf(f[j], f[j], s);
            hb[j] = bf16_rne(f[j]);
            lb[j] = bf16_rne(f[j] - bf16_to_f32(hb[j]));
        }
        *(ushort4*)(ehi + (size_t)code * D_DIM + c) = make_ushort4(hb[0], hb[1], hb[2], hb[3]);
        *(ushort4*)(elo + (size_t)code * D_DIM + c) = make_ushort4(lb[0], lb[1], lb[2], lb[3]);
    }
#pragma unroll
    for (int off = 32; off > 0; off >>= 1) s += __shfl_xor(s, off, 64);
    if (lane == 0) e2[code] = s;
}

// ---------------- split-GEMM + per-tile argmin (2-phase dbuf) -------------
__global__ __launch_bounds__(256, 2) void vq_gemm(
    const unsigned short* __restrict__ zhi, const unsigned short* __restrict__ zlo,
    const unsigned short* __restrict__ ehi, const unsigned short* __restrict__ elo,
    const float* __restrict__ e2, float* __restrict__ pv, float* __restrict__ pif) {
    // 2 buffers x 32 KB: 4 planes x [4 kchunks][128 rows] x 16B, linear
    __shared__ __align__(16) unsigned short lds[32768];
    const int AHI = 0, ALO = 4096, BHI = 8192, BLO = 12288;  // ushort offsets

    const int t = threadIdx.x, lane = t & 63, wv = t >> 6;
    // XCD-contiguous swizzle: 2048 wgs, 8 XCDs, 256 each; ntile innermost
    const int b  = blockIdx.x;
    const int wg = (b & 7) * 256 + (b >> 3);
    const int mtile = wg >> 3, ntile = wg & 7;
    const int row0 = mtile * BM;
    const int c0g  = ntile * BN;

    // staging: per wave 2 instrs/plane; 16B-slot idx = (wv*2+i)*64+lane
    const int idx0 = (wv * 2 + 0) * 64 + lane;
    const int idx1 = (wv * 2 + 1) * 64 + lane;
    const int c_0 = idx0 >> 7, r_0 = idx0 & 127;   // kchunk, row-in-tile
    const int c_1 = idx1 >> 7, r_1 = idx1 & 127;
    const size_t zo0 = (size_t)(row0 + r_0) * D_DIM + c_0 * 8;
    const size_t zo1 = (size_t)(row0 + r_1) * D_DIM + c_1 * 8;
    const size_t eo0 = (size_t)(c0g + r_0) * D_DIM + c_0 * 8;
    const size_t eo1 = (size_t)(c0g + r_1) * D_DIM + c_1 * 8;
    const int l0 = (wv * 2 + 0) * 512;   // ushort base of instr-0 chunk
    const int l1 = (wv * 2 + 1) * 512;

    const int wr = wv >> 1, wc = wv & 1;
    const int lm = lane & 15, lk = lane >> 4;

    f32x4 acc[4][4];
    const f32x4 zero4 = {0.f, 0.f, 0.f, 0.f};
#pragma unroll
    for (int i = 0; i < 4; ++i)
#pragma unroll
        for (int j = 0; j < 4; ++j) acc[i][j] = zero4;

    auto stage = [&](int kt, int bufo) {
        const int ko = kt * 32;
        GLOAD16(zhi + zo0 + ko, &lds[bufo + AHI + l0]);
        GLOAD16(zhi + zo1 + ko, &lds[bufo + AHI + l1]);
        GLOAD16(zlo + zo0 + ko, &lds[bufo + ALO + l0]);
        GLOAD16(zlo + zo1 + ko, &lds[bufo + ALO + l1]);
        GLOAD16(ehi + eo0 + ko, &lds[bufo + BHI + l0]);
        GLOAD16(ehi + eo1 + ko, &lds[bufo + BHI + l1]);
        GLOAD16(elo + eo0 + ko, &lds[bufo + BLO + l0]);
        GLOAD16(elo + eo1 + ko, &lds[bufo + BLO + l1]);
    };

    // prologue: stage tile 0 into buffer 0
    stage(0, 0);
    __syncthreads();                      // vmcnt(0) drain + barrier (once)

    int cur = 0;
    for (int kt = 0; kt < NKT; ++kt) {
        const int bufo = cur * 16384;
        // issue next tile's loads FIRST -> latency hides under 48 MFMA
        if (kt + 1 < NKT) stage(kt + 1, (cur ^ 1) * 16384);

        bf16x8 ah[4], al[4], bh[4], bl[4];
#pragma unroll
        for (int mi = 0; mi < 4; ++mi) {
            const int s = (lk * 128 + wr * 64 + mi * 16 + lm) * 8;
            ah[mi] = *(const bf16x8*)&lds[bufo + AHI + s];
            al[mi] = *(const bf16x8*)&lds[bufo + ALO + s];
        }
#pragma unroll
        for (int nj = 0; nj < 4; ++nj) {
            const int s = (lk * 128 + wc * 64 + nj * 16 + lm) * 8;
            bh[nj] = *(const bf16x8*)&lds[bufo + BHI + s];
            bl[nj] = *(const bf16x8*)&lds[bufo + BLO + s];
        }
#pragma unroll
        for (int mi = 0; mi < 4; ++mi)
#pragma unroll
            for (int nj = 0; nj < 4; ++nj)
                acc[mi][nj] = __builtin_amdgcn_mfma_f32_16x16x32_bf16(
                    ah[mi], bh[nj], acc[mi][nj], 0, 0, 0);
#pragma unroll
        for (int mi = 0; mi < 4; ++mi)
#pragma unroll
            for (int nj = 0; nj < 4; ++nj)
                acc[mi][nj] = __builtin_amdgcn_mfma_f32_16x16x32_bf16(
                    ah[mi], bl[nj], acc[mi][nj], 0, 0, 0);
#pragma unroll
        for (int mi = 0; mi < 4; ++mi)
#pragma unroll
            for (int nj = 0; nj < 4; ++nj)
                acc[mi][nj] = __builtin_amdgcn_mfma_f32_16x16x32_bf16(
                    al[mi], bh[nj], acc[mi][nj], 0, 0, 0);

        // one barrier per k-tile: stage(t+1) landed AND all reads of buf done
        __syncthreads();
        cur ^= 1;
    }

    // ---- epilogue: score + per-row argmin over this 128-code tile ----
    // D mapping (16x16x32 bf16): col=lane&15 (code), row=(lane>>4)*4+reg (z-row)
    float best[16], bidx[16];
#pragma unroll
    for (int i = 0; i < 16; ++i) { best[i] = INFINITY; bidx[i] = 0.f; }
#pragma unroll
    for (int nj = 0; nj < 4; ++nj) {
        const int cloc = wc * 64 + nj * 16 + lm;
        const float e2v = e2[c0g + cloc];
#pragma unroll
        for (int mi = 0; mi < 4; ++mi)
#pragma unroll
            for (int r = 0; r < 4; ++r) {
                const float sc = fmaf(-2.0f, acc[mi][nj][r], e2v);
                const int bi = mi * 4 + r;
                if (sc < best[bi]) { best[bi] = sc; bidx[bi] = (float)(c0g + cloc); }
            }
    }
#pragma unroll
    for (int off = 1; off < 16; off <<= 1) {
#pragma unroll
        for (int bi = 0; bi < 16; ++bi) {
            float v2 = __shfl_xor(best[bi], off, 64);
            float i2 = __shfl_xor(bidx[bi], off, 64);
            if (v2 < best[bi] || (v2 == best[bi] && i2 < bidx[bi])) {
                best[bi] = v2; bidx[bi] = i2;
            }
        }
    }
    __syncthreads();                 // LDS free; reuse for cross-wave reduce
    float* sv = (float*)lds;         // [2][128]
    float* si = sv + 256;
    if (lm == 0) {
#pragma unroll
        for (int mi = 0; mi < 4; ++mi)
#pragma unroll
            for (int r = 0; r < 4; ++r) {
                const int rl = wr * 64 + mi * 16 + lk * 4 + r;
                sv[wc * 128 + rl] = best[mi * 4 + r];
                si[wc * 128 + rl] = bidx[mi * 4 + r];
            }
    }
    __syncthreads();
    if (t < 128) {
        float v0 = sv[t], i0 = si[t];
        float v1 = sv[128 + t], i1 = si[128 + t];
        if (v1 < v0 || (v1 == v0 && i1 < i0)) { v0 = v1; i0 = i1; }
        pv [(size_t)ntile * N_TOK + row0 + t] = v0;
        pif[(size_t)ntile * N_TOK + row0 + t] = i0;
    }
}

// ---------------- outputs: fused 8-tile argmin + z_q, diff, ind -----------
__global__ __launch_bounds__(256) void vq_out_kernel(
    const float* __restrict__ z, const float* __restrict__ ew,
    const float* __restrict__ pv, const float* __restrict__ pif,
    float* __restrict__ indf, float* __restrict__ zq, float* __restrict__ diff) {
    const int w    = threadIdx.x >> 6;
    const int lane = threadIdx.x & 63;
    const int row  = blockIdx.x * 4 + w;

    // reduce the 8 n-tile partials: lanes 0..7 hold tiles 0..7 (ascending ->
    // lexicographic (val, idx) keeps first-min semantics)
    float v = INFINITY, ix = 0.f;
    if (lane < 8) {
        v  = pv [(size_t)lane * N_TOK + row];
        ix = pif[(size_t)lane * N_TOK + row];
    }
#pragma unroll
    for (int off = 1; off < 8; off <<= 1) {
        float v2 = __shfl_xor(v, off, 64);
        float i2 = __shfl_xor(ix, off, 64);
        if (v2 < v || (v2 == v && i2 < ix)) { v = v2; ix = i2; }
    }
    const float ixb = __shfl(ix, 0, 64);
    const int c = (int)ixb;
    if (lane == 0) indf[row] = ixb;

    const float4* z4 = (const float4*)&z[(size_t)row * D_DIM];
    const float4* e4 = (const float4*)&ew[(size_t)c * D_DIM];
    float4* q4 = (float4*)&zq[(size_t)row * D_DIM];
    float4* d4 = (float4*)&diff[(size_t)row * D_DIM];

#pragma unroll
    for (int vv = 0; vv < 2; ++vv) {
        const int i = vv * 64 + lane;
        const float4 zv = z4[i];
        const float4 ev = e4[i];
        float4 qv, dv;
        float ax = ev.x - zv.x, ay = ev.y - zv.y, az = ev.z - zv.z, aw = ev.w - zv.w;
        qv.x = zv.x + ax; qv.y = zv.y + ay; qv.z = zv.z + az; qv.w = zv.w + aw;
        dv.x = 0.5f * (ax * ax); dv.y = 0.5f * (ay * ay);
        dv.z = 0.5f * (az * az); dv.w = 0.5f * (aw * aw);
        q4[i] = qv;
        d4[i] = dv;
    }
}

extern "C" void kernel_launch(void* const* d_in, const int* in_sizes, int n_in,
                              void* d_out, int out_size, void* d_ws, size_t ws_size,
                              hipStream_t stream) {
    const float* z  = (const float*)d_in[0];
    const float* ew = (const float*)d_in[1];
    float* out  = (float*)d_out;
    float* zq   = out;
    float* diff = out + (size_t)N_TOK * D_DIM;
    float* indf = out + (size_t)2 * N_TOK * D_DIM;

    // scratch: ehi/elo/e2 in zq region (gemm reads them; out-kernel writes zq
    // only after); zhi/zlo in diff region; pv/pif in d_ws (2 MB) since the
    // fused out-kernel reads them while writing zq.
    char* s0 = (char*)d_out;
    unsigned short* ehi = (unsigned short*)(s0);                   // 1 MB
    unsigned short* elo = (unsigned short*)(s0 + (1u << 20));      // 1 MB
    float* e2  = (float*)(s0 + (2u << 20));                        // 4 KB
    unsigned short* zhi = (unsigned short*)diff;                   // 32 MB
    unsigned short* zlo = zhi + (size_t)N_TOK * D_DIM;             // 32 MB
    float* pv  = (float*)d_ws;                                     // 1 MB
    float* pif = (float*)d_ws + (size_t)8 * N_TOK;                 // 1 MB

    hipLaunchKernelGGL(vq_zsplit, dim3(2048),        dim3(256), 0, stream, z, zhi, zlo);
    hipLaunchKernelGGL(vq_prep,   dim3(K_CODES / 4), dim3(256), 0, stream, ew, ehi, elo, e2);
    hipLaunchKernelGGL(vq_gemm,   dim3(2048),        dim3(256), 0, stream,
                       zhi, zlo, ehi, elo, e2, pv, pif);
    hipLaunchKernelGGL(vq_out_kernel, dim3(N_TOK / 4), dim3(256), 0, stream,
                       z, ew, pv, pif, indf, zq, diff);
}

// Round 6
// 191.870 us; speedup vs baseline: 1.0936x; 1.0936x over previous
//
#include <hip/hip_runtime.h>
#include <math.h>

// VQ-VAE quantize: z [8,4096,512] f32, embed_w [1024,512] f32
// out = concat(z_q, diff, ind-as-f32)
//
// bf16 split-precision MFMA:  dot ~= zhi*ehi + zhi*elo + zlo*ehi
// score = ||e||^2 - 2*dot  (row-constant ||z||^2 dropped; argmin invariant)
// gemm: 128x128 tile, 4 waves, global_load_lds staging, double-buffer with
// COUNTED vmcnt(8): next tile's loads stay in flight across the barrier
// (T3/T4 catalog recipe); setprio(1) around the MFMA cluster (T5).

#define D_DIM   512
#define K_CODES 1024
#define N_TOK   32768

#define BM 128
#define BN 128
#define NKT 16            // 512 / 32 bf16-cols per k-tile

typedef __attribute__((ext_vector_type(8))) short bf16x8;
typedef __attribute__((ext_vector_type(4))) float f32x4;

__device__ __forceinline__ unsigned short bf16_rne(float f) {
    unsigned int u = __float_as_uint(f);
    return (unsigned short)((u + 0x7FFFu + ((u >> 16) & 1u)) >> 16);
}
__device__ __forceinline__ float bf16_to_f32(unsigned short b) {
    return __uint_as_float(((unsigned int)b) << 16);
}

#define GLOAD16(gp, lp)                                                        \
    __builtin_amdgcn_global_load_lds(                                          \
        (const __attribute__((address_space(1))) void*)(gp),                   \
        (__attribute__((address_space(3))) void*)(lp), 16, 0, 0)

// ---------------- z -> zhi/zlo bf16 planes --------------------------------
__global__ __launch_bounds__(256) void vq_zsplit(const float* __restrict__ z,
                                                 unsigned short* __restrict__ zhi,
                                                 unsigned short* __restrict__ zlo) {
    const int tid = blockIdx.x * 256 + threadIdx.x;   // grid 2048
    const float4* z4 = (const float4*)z;
    ushort4* h4 = (ushort4*)zhi;
    ushort4* l4 = (ushort4*)zlo;
#pragma unroll
    for (int g = 0; g < 8; ++g) {
        const size_t i = (size_t)g * 524288 + tid;
        float4 v = z4[i];
        float f[4] = {v.x, v.y, v.z, v.w};
        unsigned short hb[4], lb[4];
#pragma unroll
        for (int j = 0; j < 4; ++j) {
            hb[j] = bf16_rne(f[j]);
            lb[j] = bf16_rne(f[j] - bf16_to_f32(hb[j]));
        }
        h4[i] = make_ushort4(hb[0], hb[1], hb[2], hb[3]);
        l4[i] = make_ushort4(lb[0], lb[1], lb[2], lb[3]);
    }
}

// ---------------- ew -> ehi/elo bf16 + e2 ---------------------------------
__global__ __launch_bounds__(256) void vq_prep(const float* __restrict__ ew,
                                               unsigned short* __restrict__ ehi,
                                               unsigned short* __restrict__ elo,
                                               float* __restrict__ e2) {
    const int wv = threadIdx.x >> 6, lane = threadIdx.x & 63;
    const int code = blockIdx.x * 4 + wv;          // grid 256
    const float* row = ew + (size_t)code * D_DIM;
    float s = 0.0f;
#pragma unroll
    for (int h = 0; h < 2; ++h) {
        const int c = h * 256 + lane * 4;
        float4 v = *(const float4*)(row + c);
        float f[4] = {v.x, v.y, v.z, v.w};
        unsigned short hb[4], lb[4];
#pragma unroll
        for (int j = 0; j < 4; ++j) {
            s = fmaf(f[j], f[j], s);
            hb[j] = bf16_rne(f[j]);
            lb[j] = bf16_rne(f[j] - bf16_to_f32(hb[j]));
        }
        *(ushort4*)(ehi + (size_t)code * D_DIM + c) = make_ushort4(hb[0], hb[1], hb[2], hb[3]);
        *(ushort4*)(elo + (size_t)code * D_DIM + c) = make_ushort4(lb[0], lb[1], lb[2], lb[3]);
    }
#pragma unroll
    for (int off = 32; off > 0; off >>= 1) s += __shfl_xor(s, off, 64);
    if (lane == 0) e2[code] = s;
}

// ---------------- split-GEMM + per-tile argmin (counted-vmcnt dbuf) -------
__global__ __launch_bounds__(256, 2) void vq_gemm(
    const unsigned short* __restrict__ zhi, const unsigned short* __restrict__ zlo,
    const unsigned short* __restrict__ ehi, const unsigned short* __restrict__ elo,
    const float* __restrict__ e2, float* __restrict__ pv, float* __restrict__ pif) {
    // 2 buffers x 32 KB: 4 planes x [4 kchunks][128 rows] x 16B, linear
    __shared__ __align__(16) unsigned short lds[32768];
    const int AHI = 0, ALO = 4096, BHI = 8192, BLO = 12288;  // ushort offsets

    const int t = threadIdx.x, lane = t & 63, wv = t >> 6;
    // XCD-contiguous swizzle: 2048 wgs, 8 XCDs, 256 each; ntile innermost
    const int b  = blockIdx.x;
    const int wg = (b & 7) * 256 + (b >> 3);
    const int mtile = wg >> 3, ntile = wg & 7;
    const int row0 = mtile * BM;
    const int c0g  = ntile * BN;

    // staging: per wave 2 instrs/plane; 16B-slot idx = (wv*2+i)*64+lane
    const int idx0 = (wv * 2 + 0) * 64 + lane;
    const int idx1 = (wv * 2 + 1) * 64 + lane;
    const int c_0 = idx0 >> 7, r_0 = idx0 & 127;   // kchunk, row-in-tile
    const int c_1 = idx1 >> 7, r_1 = idx1 & 127;
    const size_t zo0 = (size_t)(row0 + r_0) * D_DIM + c_0 * 8;
    const size_t zo1 = (size_t)(row0 + r_1) * D_DIM + c_1 * 8;
    const size_t eo0 = (size_t)(c0g + r_0) * D_DIM + c_0 * 8;
    const size_t eo1 = (size_t)(c0g + r_1) * D_DIM + c_1 * 8;
    const int l0 = (wv * 2 + 0) * 512;   // ushort base of instr-0 chunk
    const int l1 = (wv * 2 + 1) * 512;

    const int wr = wv >> 1, wc = wv & 1;
    const int lm = lane & 15, lk = lane >> 4;

    f32x4 acc[4][4];
    const f32x4 zero4 = {0.f, 0.f, 0.f, 0.f};
#pragma unroll
    for (int i = 0; i < 4; ++i)
#pragma unroll
        for (int j = 0; j < 4; ++j) acc[i][j] = zero4;

    auto stage = [&](int kt, int bufo) {
        const int ko = kt * 32;
        GLOAD16(zhi + zo0 + ko, &lds[bufo + AHI + l0]);
        GLOAD16(zhi + zo1 + ko, &lds[bufo + AHI + l1]);
        GLOAD16(zlo + zo0 + ko, &lds[bufo + ALO + l0]);
        GLOAD16(zlo + zo1 + ko, &lds[bufo + ALO + l1]);
        GLOAD16(ehi + eo0 + ko, &lds[bufo + BHI + l0]);
        GLOAD16(ehi + eo1 + ko, &lds[bufo + BHI + l1]);
        GLOAD16(elo + eo0 + ko, &lds[bufo + BLO + l0]);
        GLOAD16(elo + eo1 + ko, &lds[bufo + BLO + l1]);
    };

    auto compute = [&](int bufo) {
        bf16x8 ah[4], al[4], bh[4], bl[4];
#pragma unroll
        for (int mi = 0; mi < 4; ++mi) {
            const int s = (lk * 128 + wr * 64 + mi * 16 + lm) * 8;
            ah[mi] = *(const bf16x8*)&lds[bufo + AHI + s];
            al[mi] = *(const bf16x8*)&lds[bufo + ALO + s];
        }
#pragma unroll
        for (int nj = 0; nj < 4; ++nj) {
            const int s = (lk * 128 + wc * 64 + nj * 16 + lm) * 8;
            bh[nj] = *(const bf16x8*)&lds[bufo + BHI + s];
            bl[nj] = *(const bf16x8*)&lds[bufo + BLO + s];
        }
        __builtin_amdgcn_s_setprio(1);
#pragma unroll
        for (int mi = 0; mi < 4; ++mi)
#pragma unroll
            for (int nj = 0; nj < 4; ++nj)
                acc[mi][nj] = __builtin_amdgcn_mfma_f32_16x16x32_bf16(
                    ah[mi], bh[nj], acc[mi][nj], 0, 0, 0);
#pragma unroll
        for (int mi = 0; mi < 4; ++mi)
#pragma unroll
            for (int nj = 0; nj < 4; ++nj)
                acc[mi][nj] = __builtin_amdgcn_mfma_f32_16x16x32_bf16(
                    ah[mi], bl[nj], acc[mi][nj], 0, 0, 0);
#pragma unroll
        for (int mi = 0; mi < 4; ++mi)
#pragma unroll
            for (int nj = 0; nj < 4; ++nj)
                acc[mi][nj] = __builtin_amdgcn_mfma_f32_16x16x32_bf16(
                    al[mi], bh[nj], acc[mi][nj], 0, 0, 0);
        __builtin_amdgcn_s_setprio(0);
    };

    // prologue: two tiles in flight
    stage(0, 0);
    stage(1, 16384);

    // main loop: tiles 0..NKT-2 with counted vmcnt(8) (next tile's 8 loads
    // remain outstanding across the barrier)
    for (int kt = 0; kt < NKT - 1; ++kt) {
        const int bufo = (kt & 1) * 16384;
        asm volatile("s_waitcnt vmcnt(8)" ::: "memory");   // this tile landed
        __builtin_amdgcn_s_barrier();                      // all waves agree
        __builtin_amdgcn_sched_barrier(0);
        compute(bufo);
        __builtin_amdgcn_sched_barrier(0);
        __builtin_amdgcn_s_barrier();                      // reads of bufo done
        if (kt + 2 < NKT) stage(kt + 2, bufo);             // refill this buffer
    }
    // peeled last tile: drain fully
    {
        const int bufo = ((NKT - 1) & 1) * 16384;
        asm volatile("s_waitcnt vmcnt(0)" ::: "memory");
        __builtin_amdgcn_s_barrier();
        __builtin_amdgcn_sched_barrier(0);
        compute(bufo);
    }

    // ---- epilogue: score + per-row argmin over this 128-code tile ----
    // D mapping (16x16x32 bf16): col=lane&15 (code), row=(lane>>4)*4+reg (z-row)
    float best[16], bidx[16];
#pragma unroll
    for (int i = 0; i < 16; ++i) { best[i] = INFINITY; bidx[i] = 0.f; }
#pragma unroll
    for (int nj = 0; nj < 4; ++nj) {
        const int cloc = wc * 64 + nj * 16 + lm;
        const float e2v = e2[c0g + cloc];
#pragma unroll
        for (int mi = 0; mi < 4; ++mi)
#pragma unroll
            for (int r = 0; r < 4; ++r) {
                const float sc = fmaf(-2.0f, acc[mi][nj][r], e2v);
                const int bi = mi * 4 + r;
                if (sc < best[bi]) { best[bi] = sc; bidx[bi] = (float)(c0g + cloc); }
            }
    }
#pragma unroll
    for (int off = 1; off < 16; off <<= 1) {
#pragma unroll
        for (int bi = 0; bi < 16; ++bi) {
            float v2 = __shfl_xor(best[bi], off, 64);
            float i2 = __shfl_xor(bidx[bi], off, 64);
            if (v2 < best[bi] || (v2 == best[bi] && i2 < bidx[bi])) {
                best[bi] = v2; bidx[bi] = i2;
            }
        }
    }
    __syncthreads();                 // LDS free; reuse for cross-wave reduce
    float* sv = (float*)lds;         // [2][128]
    float* si = sv + 256;
    if (lm == 0) {
#pragma unroll
        for (int mi = 0; mi < 4; ++mi)
#pragma unroll
            for (int r = 0; r < 4; ++r) {
                const int rl = wr * 64 + mi * 16 + lk * 4 + r;
                sv[wc * 128 + rl] = best[mi * 4 + r];
                si[wc * 128 + rl] = bidx[mi * 4 + r];
            }
    }
    __syncthreads();
    if (t < 128) {
        float v0 = sv[t], i0 = si[t];
        float v1 = sv[128 + t], i1 = si[128 + t];
        if (v1 < v0 || (v1 == v0 && i1 < i0)) { v0 = v1; i0 = i1; }
        pv [(size_t)ntile * N_TOK + row0 + t] = v0;
        pif[(size_t)ntile * N_TOK + row0 + t] = i0;
    }
}

// ---------------- outputs: fused 8-tile argmin + z_q, diff, ind -----------
__global__ __launch_bounds__(256) void vq_out_kernel(
    const float* __restrict__ z, const float* __restrict__ ew,
    const float* __restrict__ pv, const float* __restrict__ pif,
    float* __restrict__ indf, float* __restrict__ zq, float* __restrict__ diff) {
    const int w    = threadIdx.x >> 6;
    const int lane = threadIdx.x & 63;
    const int row  = blockIdx.x * 4 + w;

    // reduce the 8 n-tile partials: lanes 0..7 hold tiles 0..7 (ascending ->
    // lexicographic (val, idx) keeps first-min semantics)
    float v = INFINITY, ix = 0.f;
    if (lane < 8) {
        v  = pv [(size_t)lane * N_TOK + row];
        ix = pif[(size_t)lane * N_TOK + row];
    }
#pragma unroll
    for (int off = 1; off < 8; off <<= 1) {
        float v2 = __shfl_xor(v, off, 64);
        float i2 = __shfl_xor(ix, off, 64);
        if (v2 < v || (v2 == v && i2 < ix)) { v = v2; ix = i2; }
    }
    const float ixb = __shfl(ix, 0, 64);
    const int c = (int)ixb;
    if (lane == 0) indf[row] = ixb;

    const float4* z4 = (const float4*)&z[(size_t)row * D_DIM];
    const float4* e4 = (const float4*)&ew[(size_t)c * D_DIM];
    float4* q4 = (float4*)&zq[(size_t)row * D_DIM];
    float4* d4 = (float4*)&diff[(size_t)row * D_DIM];

#pragma unroll
    for (int vv = 0; vv < 2; ++vv) {
        const int i = vv * 64 + lane;
        const float4 zv = z4[i];
        const float4 ev = e4[i];
        float4 qv, dv;
        float ax = ev.x - zv.x, ay = ev.y - zv.y, az = ev.z - zv.z, aw = ev.w - zv.w;
        qv.x = zv.x + ax; qv.y = zv.y + ay; qv.z = zv.z + az; qv.w = zv.w + aw;
        dv.x = 0.5f * (ax * ax); dv.y = 0.5f * (ay * ay);
        dv.z = 0.5f * (az * az); dv.w = 0.5f * (aw * aw);
        q4[i] = qv;
        d4[i] = dv;
    }
}

extern "C" void kernel_launch(void* const* d_in, const int* in_sizes, int n_in,
                              void* d_out, int out_size, void* d_ws, size_t ws_size,
                              hipStream_t stream) {
    const float* z  = (const float*)d_in[0];
    const float* ew = (const float*)d_in[1];
    float* out  = (float*)d_out;
    float* zq   = out;
    float* diff = out + (size_t)N_TOK * D_DIM;
    float* indf = out + (size_t)2 * N_TOK * D_DIM;

    // scratch: ehi/elo/e2 in zq region (gemm reads them; out-kernel writes zq
    // only after); zhi/zlo in diff region; pv/pif in d_ws.
    char* s0 = (char*)d_out;
    unsigned short* ehi = (unsigned short*)(s0);                   // 1 MB
    unsigned short* elo = (unsigned short*)(s0 + (1u << 20));      // 1 MB
    float* e2  = (float*)(s0 + (2u << 20));                        // 4 KB
    unsigned short* zhi = (unsigned short*)diff;                   // 32 MB
    unsigned short* zlo = zhi + (size_t)N_TOK * D_DIM;             // 32 MB
    float* pv  = (float*)d_ws;                                     // 1 MB
    float* pif = (float*)d_ws + (size_t)8 * N_TOK;                 // 1 MB

    hipLaunchKernelGGL(vq_zsplit, dim3(2048),        dim3(256), 0, stream, z, zhi, zlo);
    hipLaunchKernelGGL(vq_prep,   dim3(K_CODES / 4), dim3(256), 0, stream, ew, ehi, elo, e2);
    hipLaunchKernelGGL(vq_gemm,   dim3(2048),        dim3(256), 0, stream,
                       zhi, zlo, ehi, elo, e2, pv, pif);
    hipLaunchKernelGGL(vq_out_kernel, dim3(N_TOK / 4), dim3(256), 0, stream,
                       z, ew, pv, pif, indf, zq, diff);
}